// Round 6
// baseline (98.329 us; speedup 1.0000x reference)
//
#include <hip/hip_runtime.h>

// LIF scan, 2001 steps over 32768 fp32 neurons. Outputs (flat fp32 in d_out):
//   s_last [N], v_last [N], v_t [T*N], s_t [T*N];  N=32768, T=2001 -> 525 MB writes.
//
// Single-pass, 1 neuron/thread (no replay — round-5 lesson: replay is
// issue-bound and serializes the last chunk). 16B stores via LDS transpose:
// buffer G=8 steps in registers, transpose in LDS, store float4 of 4
// consecutive neurons. Double-buffered LDS -> 1 barrier per group.
//
// Numerics: contract(off) + explicit __fmul_rn/__fadd_rn (rounds 1/5: bit-exact
// vs numpy mul-then-add; round 2: default contract=fast flips spikes).
// No nontemporal stores (round 4: NT caps write BW at ~5.4 TB/s).

#pragma clang fp contract(off)

typedef float f32x4 __attribute__((ext_vector_type(4)));

#define T_STEPS  2001
#define G        8
#define NGROUPS  250      // 250*8 = 2000 steps; +1 epilogue step

__global__ __launch_bounds__(128) void lif_lds_kernel(
    const float* __restrict__ x,
    float* __restrict__ s_last,
    float* __restrict__ v_last,
    float* __restrict__ v_t,
    float* __restrict__ s_t,
    int n)                                  // 32768
{
    #pragma clang fp contract(off)

    // [double-buffer][array: 0=v 1=s][step*128 + neuron]
    __shared__ __align__(16) float lds[2][2][G * 128];

    const int t   = threadIdx.x;            // 0..127
    const int bid = blockIdx.x;             // 0..255 (1 block/CU)
    const int gid = bid * 128 + t;
    const int n4  = n >> 2;                 // 8192 float4 per row

    f32x4* __restrict__ v_t4 = (f32x4*)v_t;
    f32x4* __restrict__ s_t4 = (f32x4*)s_t;

    const float dr = __fmul_rn(0.05f, x[gid]);  // bit-exact hoist
    float v = 0.f;

    for (int tg = 0; tg < NGROUPS; ++tg) {
        const int db = tg & 1;

        // ---- compute G steps into registers (statically indexed) ----
        float vb[G], sb[G];
        #pragma unroll
        for (int j = 0; j < G; ++j) {
            float u = __fadd_rn(__fmul_rn(0.95f, v), dr);
            bool  k = u > 0.3f;
            v     = k ? 0.f : u;
            vb[j] = v;
            sb[j] = k ? 1.f : 0.f;
        }

        // ---- LDS write: [step][neuron], lane-stride-1 -> conflict-free ----
        #pragma unroll
        for (int j = 0; j < G; ++j) {
            lds[db][0][j * 128 + t] = vb[j];
            lds[db][1][j * 128 + t] = sb[j];
        }
        __syncthreads();
        // (no 2nd barrier: next group writes lds[db^1]; a wave re-writes
        //  lds[db] only after the NEXT barrier, which orders all reads here)

        // ---- transposed float4 stores: 512 units = 2 arrays x 8 steps x 32 quads
        const int t0 = tg * G;
        #pragma unroll
        for (int k = 0; k < 4; ++k) {
            const int u    = t + k * 128;
            const int quad = u & 31;
            const int step = (u >> 5) & (G - 1);
            const int arr  = u >> 8;                       // 0: v_t, 1: s_t
            const f32x4* lv = (const f32x4*)&lds[db][arr][0];
            const f32x4  val = lv[step * 32 + quad];       // 16B contiguous/lane
            f32x4* dst = arr ? s_t4 : v_t4;
            dst[(size_t)(t0 + step) * n4 + bid * 32 + quad] = val;
        }
    }

    // ---- epilogue: final step (t = 2000), scalar stores (256 KB total) ----
    {
        float u = __fadd_rn(__fmul_rn(0.95f, v), dr);
        bool  k = u > 0.3f;
        v = k ? 0.f : u;
        const float s = k ? 1.f : 0.f;
        v_t[(size_t)2000 * n + gid] = v;
        s_t[(size_t)2000 * n + gid] = s;
        s_last[gid] = s;    // s_t[-1]
        v_last[gid] = v;    // final carry
    }
}

extern "C" void kernel_launch(void* const* d_in, const int* in_sizes, int n_in,
                              void* d_out, int out_size, void* d_ws, size_t ws_size,
                              hipStream_t stream)
{
    const float* x = (const float*)d_in[0];
    const int n = in_sizes[0];               // 32768

    float* out    = (float*)d_out;
    float* s_last = out;
    float* v_last = out + n;
    float* v_t    = out + 2 * (size_t)n;
    float* s_t    = out + 2 * (size_t)n + (size_t)T_STEPS * (size_t)n;

    const int block = 128;
    const int grid  = n / block;             // 256 blocks -> 1 per CU
    lif_lds_kernel<<<grid, block, 0, stream>>>(x, s_last, v_last, v_t, s_t, n);
}